// Round 5
// baseline (244.267 us; speedup 1.0000x reference)
//
#include <hip/hip_runtime.h>
#include <stdint.h>

#define F_DIM 128
#define H_DIM 64
#define K_DIM 16
#define BUK_SH 8
#define NCH 256

typedef _Float16 half2v __attribute__((ext_vector_type(2)));
typedef _Float16 half4 __attribute__((ext_vector_type(4)));
typedef _Float16 f16x8 __attribute__((ext_vector_type(8)));
typedef float f32x4 __attribute__((ext_vector_type(4)));

// 16B global->LDS DMA: LDS dest = wave-uniform base + lane*16, global src per-lane
__device__ __forceinline__ void gload_lds16(const void* g, void* l) {
    __builtin_amdgcn_global_load_lds(
        (const __attribute__((address_space(1))) void*)g,
        (__attribute__((address_space(3))) void*)l, 16, 0, 0);
}

// ---- radix-partition CSR build (5 kernels) -----------------------------
__global__ __launch_bounds__(256) void k_hist(const int* __restrict__ dst,
                                              int* __restrict__ hist,
                                              int E, int CH, int NBUK) {
    __shared__ int h[512];
    int t = threadIdx.x, c = blockIdx.x;
    for (int i = t; i < NBUK; i += 256) h[i] = 0;
    __syncthreads();
    int s = c * CH, e = min(s + CH, E);
    for (int i = s + t; i < e; i += 256) atomicAdd(&h[dst[i] >> BUK_SH], 1);
    __syncthreads();
    for (int i = t; i < NBUK; i += 256) hist[i * NCH + c] = h[i];
}

__global__ __launch_bounds__(256) void k_scanBkt(int* __restrict__ hist,
                                                 int* __restrict__ bktTot) {
    __shared__ int sh[256];
    int b = blockIdx.x, t = threadIdx.x;
    int v = hist[b * NCH + t];
    sh[t] = v;
    __syncthreads();
    for (int off = 1; off < 256; off <<= 1) {
        int x = (t >= off) ? sh[t - off] : 0;
        __syncthreads();
        sh[t] += x;
        __syncthreads();
    }
    hist[b * NCH + t] = sh[t] - v;
    if (t == 255) bktTot[b] = sh[255];
}

__global__ __launch_bounds__(256) void k_scanTot(const int* __restrict__ bktTot,
                                                 int* __restrict__ bktBase, int NBUK) {
    __shared__ int sh[256];
    int t = threadIdx.x;
    int i0 = 2 * t, i1 = 2 * t + 1;
    int v0 = (i0 < NBUK) ? bktTot[i0] : 0;
    int v1 = (i1 < NBUK) ? bktTot[i1] : 0;
    int s = v0 + v1;
    sh[t] = s;
    __syncthreads();
    for (int off = 1; off < 256; off <<= 1) {
        int x = (t >= off) ? sh[t - off] : 0;
        __syncthreads();
        sh[t] += x;
        __syncthreads();
    }
    int excl = sh[t] - s;
    if (i0 < NBUK) bktBase[i0] = excl;
    if (i1 < NBUK) bktBase[i1] = excl + v0;
    if (t == 255) bktBase[NBUK] = sh[255];
}

__global__ __launch_bounds__(256) void k_scatter(const int* __restrict__ src,
                                                 const int* __restrict__ dst,
                                                 const int* __restrict__ hist,
                                                 const int* __restrict__ bktBase,
                                                 uint32_t* __restrict__ binned,
                                                 int E, int CH, int NBUK) {
    __shared__ int ctr[512];
    int t = threadIdx.x, c = blockIdx.x;
    for (int i = t; i < NBUK; i += 256) ctr[i] = bktBase[i] + hist[i * NCH + c];
    __syncthreads();
    int s = c * CH, e = min(s + CH, E);
    for (int i = s + t; i < e; i += 256) {
        int d = dst[i];
        int pos = atomicAdd(&ctr[d >> BUK_SH], 1);
        binned[pos] = (uint32_t)src[i] | ((uint32_t)(d & 255) << 20);
    }
}

__global__ __launch_bounds__(256) void k_fine2(const uint32_t* __restrict__ binned,
                                               const int* __restrict__ bktBase,
                                               int* __restrict__ rowptr,
                                               int* __restrict__ col, int N) {
    __shared__ int h[256], sc[256], slotL[256];
    int b = blockIdx.x, t = threadIdx.x;
    int n0 = b << BUK_SH;
    int s = bktBase[b], e = bktBase[b + 1];
    h[t] = 0;
    __syncthreads();
    for (int i = s + t; i < e; i += 256) atomicAdd(&h[binned[i] >> 20], 1);
    __syncthreads();
    int v = h[t];
    sc[t] = v;
    __syncthreads();
    for (int off = 1; off < 256; off <<= 1) {
        int x = (t >= off) ? sc[t - off] : 0;
        __syncthreads();
        sc[t] += x;
        __syncthreads();
    }
    int excl = sc[t] - v;
    int n = n0 + t;
    int rowbase = s + n0;
    if (n < N) {
        int rp = rowbase + excl + t;
        rowptr[n] = rp;
        col[rp] = n;
        slotL[t] = rp + 1;
        if (n == N - 1) rowptr[N] = rp + v + 1;
    }
    __syncthreads();
    for (int i = s + t; i < e; i += 256) {
        uint32_t p = binned[i];
        int pos = atomicAdd(&slotL[p >> 20], 1);
        col[pos] = (int)(p & 0xFFFFFu);
    }
}

// ---- W pre-swizzle: fp32 -> fp16 MFMA-fragment layout, done ONCE -------
__global__ __launch_bounds__(256) void k_swzW(const float* __restrict__ W1l,
                                              const float* __restrict__ W1r,
                                              const float* __restrict__ W2l,
                                              const float* __restrict__ W2r,
                                              _Float16* __restrict__ Wg1,
                                              _Float16* __restrict__ Wg2) {
    int t = threadIdx.x;
    if (blockIdx.x == 0) {
        for (int i = t; i < 4096; i += 256) {
            int k = i >> 5, c4 = (i & 31) << 2;
            float4 v = (c4 < 64) ? *(const float4*)&W1l[k * 64 + c4]
                                 : *(const float4*)&W1r[k * 64 + (c4 - 64)];
            int s = k >> 5, q = (k >> 3) & 3, j = k & 7;
            float vv[4] = {v.x, v.y, v.z, v.w};
#pragma unroll
            for (int u = 0; u < 4; ++u) {
                int C = c4 + u, c = C >> 4, n = C & 15;
                Wg1[(((c * 4 + s) * 4 + q) * 16 + n) * 8 + j] = (_Float16)vv[u];
            }
        }
    } else {
        for (int i = t; i < 512; i += 256) {
            int k = i >> 3, c4 = (i & 7) << 2;
            float4 v = (c4 < 16) ? *(const float4*)&W2l[k * 16 + c4]
                                 : *(const float4*)&W2r[k * 16 + (c4 - 16)];
            int s = k >> 5, q = (k >> 3) & 3, j = k & 7;
            float vv[4] = {v.x, v.y, v.z, v.w};
#pragma unroll
            for (int u = 0; u < 4; ++u) {
                int C = c4 + u, c = C >> 4, n = C & 15;
                Wg2[(((c * 2 + s) * 4 + q) * 16 + n) * 8 + j] = (_Float16)vv[u];
            }
        }
    }
}

// ---- Layer 1 GEMM: 32 rows/block, c-split wave pairs, W via LDS-DMA ----
__global__ __launch_bounds__(256, 4) void k_gemm1m(
        const float* __restrict__ X, const _Float16* __restrict__ Wg,
        _Float16* __restrict__ xlh, _Float16* __restrict__ xrh, int N) {
    __shared__ _Float16 Ws[16384];        // 32 KB: W frags, reused for epilogue
    int t = threadIdx.x;
    int n0 = blockIdx.x * 32;
    int w = t >> 6, lane = t & 63, m = lane & 15, q = lane >> 4;
    int rowHalf = w >> 1, cHalf = w & 1;
    // DMA-stage the 32 KB W table: 2048 x 16B chunks, 8 per thread
    {
        int base = w * 64;                // chunk index of this wave's lane 0
#pragma unroll
        for (int i = 0; i < 8; ++i) {
            int ch = i * 256 + base;
            gload_lds16(&Wg[(long)(ch + lane) * 8], &Ws[(long)ch * 8]);
        }
    }
    // prefetch this wave's 16 X rows (fp32), all 8 loads co-outstanding
    int r0 = n0 + rowHalf * 16 + m;
    int rc = (r0 < N) ? r0 : (N - 1);
    const float* p0 = X + (long)rc * 128 + q * 8;
    float4 xf[8];
#pragma unroll
    for (int s = 0; s < 4; ++s) {
        xf[2 * s]     = *(const float4*)(p0 + s * 32);
        xf[2 * s + 1] = *(const float4*)(p0 + s * 32 + 4);
    }
    f16x8 af[4];
#pragma unroll
    for (int s = 0; s < 4; ++s) {
        af[s][0] = (_Float16)xf[2 * s].x;     af[s][1] = (_Float16)xf[2 * s].y;
        af[s][2] = (_Float16)xf[2 * s].z;     af[s][3] = (_Float16)xf[2 * s].w;
        af[s][4] = (_Float16)xf[2 * s + 1].x; af[s][5] = (_Float16)xf[2 * s + 1].y;
        af[s][6] = (_Float16)xf[2 * s + 1].z; af[s][7] = (_Float16)xf[2 * s + 1].w;
    }
    __syncthreads();                      // drains the W DMA (vmcnt) + all waves
    f32x4 acc[4];
#pragma unroll
    for (int c = 0; c < 4; ++c) acc[c] = (f32x4){0.f, 0.f, 0.f, 0.f};
#pragma unroll
    for (int s = 0; s < 4; ++s)
#pragma unroll
        for (int c = 0; c < 4; ++c) {
            int cc = cHalf * 4 + c;
            f16x8 b = *(const f16x8*)&Ws[(((cc * 4 + s) * 4 + q) * 16 + m) * 8];
            acc[c] = __builtin_amdgcn_mfma_f32_16x16x32_f16(af[s], b, acc[c], 0, 0, 0);
        }
    __syncthreads();                      // all waves done reading Ws
    // per-wave transpose region (16 rows x 64 cols, stride 76 halves)
    _Float16* Tw = &Ws[w * 2048];
#pragma unroll
    for (int c = 0; c < 4; ++c)
#pragma unroll
        for (int r = 0; r < 4; ++r)
            Tw[(q * 4 + r) * 76 + c * 16 + m] = (_Float16)acc[c][r];
    // coalesced stores: wave writes 8 rows x 128B contiguous per pass
#pragma unroll
    for (int p = 0; p < 2; ++p) {
        int lr = p * 8 + (lane >> 3);
        int chk = lane & 7;
        f16x8 v = *(const f16x8*)&Tw[lr * 76 + chk * 8];
        int gn = n0 + rowHalf * 16 + lr;
        if (gn < N) {
            if (cHalf == 0) *(f16x8*)&xlh[(long)gn * 64 + chk * 8] = v;
            else            *(f16x8*)&xrh[(long)gn * 64 + chk * 8] = v;
        }
    }
}

// ---- Layer 2 GEMM: 32 rows/wave, W2 staged in LDS, H prefetched --------
__global__ __launch_bounds__(256, 4) void k_gemm2m(
        const _Float16* __restrict__ Hm, const _Float16* __restrict__ Wg2,
        _Float16* __restrict__ xlh, _Float16* __restrict__ xrh, int N) {
    __shared__ _Float16 Ws2[1024];        // 2 KB W frags
    __shared__ _Float16 T[4][32 * 40];    // per-wave transpose, stride 40
    int t = threadIdx.x;
    int n0 = blockIdx.x * 128;
    int w = t >> 6, lane = t & 63, m = lane & 15, q = lane >> 4;
    if (t < 128) *(f16x8*)&Ws2[t * 8] = *(const f16x8*)&Wg2[t * 8];
    // prefetch H fragments: 2 subs x 2 s-steps (all in flight)
    const f16x8 zh = {0, 0, 0, 0, 0, 0, 0, 0};
    f16x8 a[2][2];
#pragma unroll
    for (int sub = 0; sub < 2; ++sub) {
        int row = n0 + w * 32 + sub * 16 + m;
        bool vr = row < N;
#pragma unroll
        for (int s = 0; s < 2; ++s)
            a[sub][s] = vr ? *(const f16x8*)&Hm[(long)row * 64 + s * 32 + q * 8] : zh;
    }
    __syncthreads();
    f32x4 acc[2][2];
#pragma unroll
    for (int sub = 0; sub < 2; ++sub)
#pragma unroll
        for (int c = 0; c < 2; ++c) acc[sub][c] = (f32x4){0.f, 0.f, 0.f, 0.f};
#pragma unroll
    for (int s = 0; s < 2; ++s)
#pragma unroll
        for (int c = 0; c < 2; ++c) {
            f16x8 b = *(const f16x8*)&Ws2[(((c * 2 + s) * 4 + q) * 16 + m) * 8];
#pragma unroll
            for (int sub = 0; sub < 2; ++sub)
                acc[sub][c] = __builtin_amdgcn_mfma_f32_16x16x32_f16(a[sub][s], b, acc[sub][c], 0, 0, 0);
        }
    _Float16* Tw = T[w];
#pragma unroll
    for (int sub = 0; sub < 2; ++sub)
#pragma unroll
    for (int c = 0; c < 2; ++c)
#pragma unroll
    for (int r = 0; r < 4; ++r)
        Tw[(sub * 16 + q * 4 + r) * 40 + c * 16 + m] = (_Float16)acc[sub][c][r];
    int lr = lane >> 1;
    int gn = n0 + w * 32 + lr;
#pragma unroll
    for (int p = 0; p < 2; ++p) {
        int cc = p * 2 + (lane & 1);
        f16x8 v = *(const f16x8*)&Tw[lr * 40 + cc * 8];
        if (gn < N) {
            if (cc < 2) *(f16x8*)&xlh[(long)gn * 16 + cc * 8] = v;
            else        *(f16x8*)&xrh[(long)gn * 16 + (cc - 2) * 8] = v;
        }
    }
}

// ---- Attention layer 1: 16 lanes/node (4 nodes/wave), 4-edge ILP -------
// lane layout: [node_sub 2b][g 1b][q 3b]; q = dim octet, g = edge group.
// Main loop keeps 4 independent gather->dot->shuffle->exp chains in flight
// so the ds-pipe shuffle latency is hidden by ILP.
__global__ void k_att1(const f16x8* __restrict__ xlh, const f16x8* __restrict__ xrh,
                       const float* __restrict__ a1, const float* __restrict__ b1,
                       const int* __restrict__ rowptr, const int* __restrict__ col,
                       f16x8* __restrict__ hout, int N) {
    int n = (int)((blockIdx.x * (unsigned)blockDim.x + threadIdx.x) >> 4);
    int lane = threadIdx.x & 63;
    if (n >= N) return;
    int q = lane & 7;          // dim octet: dims q*8 .. q*8+7
    int g = (lane >> 3) & 1;   // edge group 0..1
    float4 af0 = ((const float4*)a1)[q * 2 + 0];
    float4 af1 = ((const float4*)a1)[q * 2 + 1];
    half2v a01 = {(_Float16)af0.x, (_Float16)af0.y};
    half2v a23 = {(_Float16)af0.z, (_Float16)af0.w};
    half2v a45 = {(_Float16)af1.x, (_Float16)af1.y};
    half2v a67 = {(_Float16)af1.z, (_Float16)af1.w};
    f16x8 xrv = xrh[(long)n * 8 + q];
    int jb = rowptr[n], je = rowptr[n + 1];
    float l = 0.f;
    float o[8] = {0.f, 0.f, 0.f, 0.f, 0.f, 0.f, 0.f, 0.f};
    int j = jb + g;
    // main: 4 edges per group per iteration (group's edges are stride-2)
    for (; j + 6 < je; j += 8) {
        int s0 = col[j], s1 = col[j + 2], s2 = col[j + 4], s3 = col[j + 6];
        f16x8 xh0 = xlh[(long)s0 * 8 + q];
        f16x8 xh1 = xlh[(long)s1 * 8 + q];
        f16x8 xh2 = xlh[(long)s2 * 8 + q];
        f16x8 xh3 = xlh[(long)s3 * 8 + q];
        f16x8 t0 = xh0 + xrv, t1 = xh1 + xrv, t2 = xh2 + xrv, t3 = xh3 + xrv;
        f16x8 u0 = __builtin_elementwise_max(t0, t0 * (_Float16)0.2f);
        f16x8 u1 = __builtin_elementwise_max(t1, t1 * (_Float16)0.2f);
        f16x8 u2 = __builtin_elementwise_max(t2, t2 * (_Float16)0.2f);
        f16x8 u3 = __builtin_elementwise_max(t3, t3 * (_Float16)0.2f);
        half2v u0a = {u0[0], u0[1]}, u0b = {u0[2], u0[3]}, u0c = {u0[4], u0[5]}, u0d = {u0[6], u0[7]};
        half2v u1a = {u1[0], u1[1]}, u1b = {u1[2], u1[3]}, u1c = {u1[4], u1[5]}, u1d = {u1[6], u1[7]};
        half2v u2a = {u2[0], u2[1]}, u2b = {u2[2], u2[3]}, u2c = {u2[4], u2[5]}, u2d = {u2[6], u2[7]};
        half2v u3a = {u3[0], u3[1]}, u3b = {u3[2], u3[3]}, u3c = {u3[4], u3[5]}, u3d = {u3[6], u3[7]};
        float e0 = __builtin_amdgcn_fdot2(u0a, a01,
                    __builtin_amdgcn_fdot2(u0b, a23,
                     __builtin_amdgcn_fdot2(u0c, a45,
                      __builtin_amdgcn_fdot2(u0d, a67, 0.f, false), false), false), false);
        float e1 = __builtin_amdgcn_fdot2(u1a, a01,
                    __builtin_amdgcn_fdot2(u1b, a23,
                     __builtin_amdgcn_fdot2(u1c, a45,
                      __builtin_amdgcn_fdot2(u1d, a67, 0.f, false), false), false), false);
        float e2 = __builtin_amdgcn_fdot2(u2a, a01,
                    __builtin_amdgcn_fdot2(u2b, a23,
                     __builtin_amdgcn_fdot2(u2c, a45,
                      __builtin_amdgcn_fdot2(u2d, a67, 0.f, false), false), false), false);
        float e3 = __builtin_amdgcn_fdot2(u3a, a01,
                    __builtin_amdgcn_fdot2(u3b, a23,
                     __builtin_amdgcn_fdot2(u3c, a45,
                      __builtin_amdgcn_fdot2(u3d, a67, 0.f, false), false), false), false);
#pragma unroll
        for (int off = 1; off < 8; off <<= 1) {
            e0 += __shfl_xor(e0, off, 8);
            e1 += __shfl_xor(e1, off, 8);
            e2 += __shfl_xor(e2, off, 8);
            e3 += __shfl_xor(e3, off, 8);
        }
        float c0 = __expf(e0), c1 = __expf(e1), c2 = __expf(e2), c3 = __expf(e3);
        l += (c0 + c1) + (c2 + c3);
#pragma unroll
        for (int i = 0; i < 8; ++i)
            o[i] = fmaf(c0, (float)xh0[i],
                    fmaf(c1, (float)xh1[i],
                     fmaf(c2, (float)xh2[i],
                      fmaf(c3, (float)xh3[i], o[i]))));
    }
    // mid: 2 edges
    for (; j + 2 < je; j += 4) {
        int s0 = col[j], s1 = col[j + 2];
        f16x8 xh0 = xlh[(long)s0 * 8 + q];
        f16x8 xh1 = xlh[(long)s1 * 8 + q];
        f16x8 t0 = xh0 + xrv, t1 = xh1 + xrv;
        f16x8 u0 = __builtin_elementwise_max(t0, t0 * (_Float16)0.2f);
        f16x8 u1 = __builtin_elementwise_max(t1, t1 * (_Float16)0.2f);
        half2v u0a = {u0[0], u0[1]}, u0b = {u0[2], u0[3]}, u0c = {u0[4], u0[5]}, u0d = {u0[6], u0[7]};
        half2v u1a = {u1[0], u1[1]}, u1b = {u1[2], u1[3]}, u1c = {u1[4], u1[5]}, u1d = {u1[6], u1[7]};
        float e0 = __builtin_amdgcn_fdot2(u0a, a01,
                    __builtin_amdgcn_fdot2(u0b, a23,
                     __builtin_amdgcn_fdot2(u0c, a45,
                      __builtin_amdgcn_fdot2(u0d, a67, 0.f, false), false), false), false);
        float e1 = __builtin_amdgcn_fdot2(u1a, a01,
                    __builtin_amdgcn_fdot2(u1b, a23,
                     __builtin_amdgcn_fdot2(u1c, a45,
                      __builtin_amdgcn_fdot2(u1d, a67, 0.f, false), false), false), false);
#pragma unroll
        for (int off = 1; off < 8; off <<= 1) {
            e0 += __shfl_xor(e0, off, 8);
            e1 += __shfl_xor(e1, off, 8);
        }
        float c0 = __expf(e0), c1 = __expf(e1);
        l += c0 + c1;
#pragma unroll
        for (int i = 0; i < 8; ++i)
            o[i] = fmaf(c0, (float)xh0[i], fmaf(c1, (float)xh1[i], o[i]));
    }
    // tail: at most one edge per group
    for (; j < je; j += 2) {
        int s = col[j];
        f16x8 xh = xlh[(long)s * 8 + q];
        f16x8 t = xh + xrv;
        f16x8 u = __builtin_elementwise_max(t, t * (_Float16)0.2f);
        half2v ua = {u[0], u[1]}, ub = {u[2], u[3]}, uc = {u[4], u[5]}, ud = {u[6], u[7]};
        float e = __builtin_amdgcn_fdot2(ua, a01,
                   __builtin_amdgcn_fdot2(ub, a23,
                    __builtin_amdgcn_fdot2(uc, a45,
                     __builtin_amdgcn_fdot2(ud, a67, 0.f, false), false), false), false);
#pragma unroll
        for (int off = 1; off < 8; off <<= 1) e += __shfl_xor(e, off, 8);
        float c = __expf(e);
        l += c;
#pragma unroll
        for (int i = 0; i < 8; ++i) o[i] = fmaf(c, (float)xh[i], o[i]);
    }
    l += __shfl_xor(l, 8);
#pragma unroll
    for (int i = 0; i < 8; ++i) o[i] += __shfl_xor(o[i], 8);
    if (g == 0) {
        float4 bv0 = ((const float4*)b1)[q * 2 + 0];
        float4 bv1 = ((const float4*)b1)[q * 2 + 1];
        float bb[8] = {bv0.x, bv0.y, bv0.z, bv0.w, bv1.x, bv1.y, bv1.z, bv1.w};
        float rl = 1.f / l;
        f16x8 hv;
#pragma unroll
        for (int i = 0; i < 8; ++i) {
            float h = o[i] * rl + bb[i];
            h = (h > 0.f) ? h : (__expf(h) - 1.f);
            hv[i] = (_Float16)h;
        }
        hout[(long)n * 8 + q] = hv;
    }
}

// ---- Attention layer 2 + softmax: 16 lanes/node, 4-edge ILP ------------
// lane layout: [node_sub 2b][g 2b][q 2b]; q = dim quad, g = edge group 0..3.
__global__ void k_att2(const half4* __restrict__ xlh, const half4* __restrict__ xrh,
                       const float* __restrict__ a2, const float* __restrict__ b2v,
                       const int* __restrict__ rowptr, const int* __restrict__ col,
                       float* __restrict__ out, int N) {
    int n = (int)((blockIdx.x * (unsigned)blockDim.x + threadIdx.x) >> 4);
    int lane = threadIdx.x & 63;
    if (n >= N) return;
    int q = lane & 3;
    int g = (lane >> 2) & 3;
    float4 af = ((const float4*)a2)[q];
    half2v alo = {(_Float16)af.x, (_Float16)af.y};
    half2v ahi = {(_Float16)af.z, (_Float16)af.w};
    half4 xrv = xrh[(long)n * 4 + q];
    int jb = rowptr[n], je = rowptr[n + 1];
    float l = 0.f;
    float4 o = {0.f, 0.f, 0.f, 0.f};
    int j = jb + g;
    // main: 4 edges per group per iteration (group's edges are stride-4)
    for (; j + 12 < je; j += 16) {
        int s0 = col[j], s1 = col[j + 4], s2 = col[j + 8], s3 = col[j + 12];
        half4 xh0 = xlh[(long)s0 * 4 + q];
        half4 xh1 = xlh[(long)s1 * 4 + q];
        half4 xh2 = xlh[(long)s2 * 4 + q];
        half4 xh3 = xlh[(long)s3 * 4 + q];
        half4 t0 = xh0 + xrv, t1 = xh1 + xrv, t2 = xh2 + xrv, t3 = xh3 + xrv;
        half4 u0 = __builtin_elementwise_max(t0, t0 * (_Float16)0.2f);
        half4 u1 = __builtin_elementwise_max(t1, t1 * (_Float16)0.2f);
        half4 u2 = __builtin_elementwise_max(t2, t2 * (_Float16)0.2f);
        half4 u3 = __builtin_elementwise_max(t3, t3 * (_Float16)0.2f);
        half2v u0lo = {u0.x, u0.y}, u0hi = {u0.z, u0.w};
        half2v u1lo = {u1.x, u1.y}, u1hi = {u1.z, u1.w};
        half2v u2lo = {u2.x, u2.y}, u2hi = {u2.z, u2.w};
        half2v u3lo = {u3.x, u3.y}, u3hi = {u3.z, u3.w};
        float e0 = __builtin_amdgcn_fdot2(u0lo, alo,
                    __builtin_amdgcn_fdot2(u0hi, ahi, 0.f, false), false);
        float e1 = __builtin_amdgcn_fdot2(u1lo, alo,
                    __builtin_amdgcn_fdot2(u1hi, ahi, 0.f, false), false);
        float e2 = __builtin_amdgcn_fdot2(u2lo, alo,
                    __builtin_amdgcn_fdot2(u2hi, ahi, 0.f, false), false);
        float e3 = __builtin_amdgcn_fdot2(u3lo, alo,
                    __builtin_amdgcn_fdot2(u3hi, ahi, 0.f, false), false);
        e0 += __shfl_xor(e0, 1, 4); e1 += __shfl_xor(e1, 1, 4);
        e2 += __shfl_xor(e2, 1, 4); e3 += __shfl_xor(e3, 1, 4);
        e0 += __shfl_xor(e0, 2, 4); e1 += __shfl_xor(e1, 2, 4);
        e2 += __shfl_xor(e2, 2, 4); e3 += __shfl_xor(e3, 2, 4);
        float c0 = __expf(e0), c1 = __expf(e1), c2 = __expf(e2), c3 = __expf(e3);
        l += (c0 + c1) + (c2 + c3);
        o.x = fmaf(c0, (float)xh0.x, fmaf(c1, (float)xh1.x,
               fmaf(c2, (float)xh2.x, fmaf(c3, (float)xh3.x, o.x))));
        o.y = fmaf(c0, (float)xh0.y, fmaf(c1, (float)xh1.y,
               fmaf(c2, (float)xh2.y, fmaf(c3, (float)xh3.y, o.y))));
        o.z = fmaf(c0, (float)xh0.z, fmaf(c1, (float)xh1.z,
               fmaf(c2, (float)xh2.z, fmaf(c3, (float)xh3.z, o.z))));
        o.w = fmaf(c0, (float)xh0.w, fmaf(c1, (float)xh1.w,
               fmaf(c2, (float)xh2.w, fmaf(c3, (float)xh3.w, o.w))));
    }
    for (; j < je; j += 4) {
        int s = col[j];
        half4 xh = xlh[(long)s * 4 + q];
        half4 t = xh + xrv;
        half4 u = __builtin_elementwise_max(t, t * (_Float16)0.2f);
        half2v ulo = {u.x, u.y}, uhi = {u.z, u.w};
        float e = __builtin_amdgcn_fdot2(ulo, alo,
                   __builtin_amdgcn_fdot2(uhi, ahi, 0.f, false), false);
        e += __shfl_xor(e, 1, 4);
        e += __shfl_xor(e, 2, 4);
        float c = __expf(e);
        l += c;
        o.x = fmaf(c, (float)xh.x, o.x);
        o.y = fmaf(c, (float)xh.y, o.y);
        o.z = fmaf(c, (float)xh.z, o.z);
        o.w = fmaf(c, (float)xh.w, o.w);
    }
#pragma unroll
    for (int off = 4; off <= 8; off <<= 1) {
        l   += __shfl_xor(l, off);
        o.x += __shfl_xor(o.x, off);
        o.y += __shfl_xor(o.y, off);
        o.z += __shfl_xor(o.z, off);
        o.w += __shfl_xor(o.w, off);
    }
    if (g == 0) {
        float4 bv = ((const float4*)b2v)[q];
        float rl = 1.f / l;
        float4 z;
        z.x = o.x * rl + bv.x;
        z.y = o.y * rl + bv.y;
        z.z = o.z * rl + bv.z;
        z.w = o.w * rl + bv.w;
        float mx = fmaxf(fmaxf(z.x, z.y), fmaxf(z.z, z.w));
        mx = fmaxf(mx, __shfl_xor(mx, 1, 4));
        mx = fmaxf(mx, __shfl_xor(mx, 2, 4));
        float4 ez;
        ez.x = __expf(z.x - mx); ez.y = __expf(z.y - mx);
        ez.z = __expf(z.z - mx); ez.w = __expf(z.w - mx);
        float ss = ez.x + ez.y + ez.z + ez.w;
        ss += __shfl_xor(ss, 1, 4);
        ss += __shfl_xor(ss, 2, 4);
        float rs = 1.f / ss;
        ez.x *= rs; ez.y *= rs; ez.z *= rs; ez.w *= rs;
        ((float4*)out)[(long)n * 4 + q] = ez;
    }
}

// ---- launch ------------------------------------------------------------
extern "C" void kernel_launch(void* const* d_in, const int* in_sizes, int n_in,
                              void* d_out, int out_size, void* d_ws, size_t ws_size,
                              hipStream_t stream) {
    const float* X   = (const float*)d_in[0];
    const int*   ei  = (const int*)d_in[1];
    const float* W1l = (const float*)d_in[3];
    const float* W1r = (const float*)d_in[4];
    const float* a1  = (const float*)d_in[5];
    const float* b1  = (const float*)d_in[6];
    const float* W2l = (const float*)d_in[7];
    const float* W2r = (const float*)d_in[8];
    const float* a2  = (const float*)d_in[9];
    const float* b2  = (const float*)d_in[10];

    int N = in_sizes[0] / F_DIM;
    int E = in_sizes[1] / 2;
    int M = E + N;
    int NBUK = (N + 255) >> BUK_SH;
    int NH = NBUK * NCH;
    int CH = (E + NCH - 1) / NCH;
    const int* srcv = ei;
    const int* dstv = ei + E;

    char* w = (char*)d_ws;
    size_t off = 0;
    auto alloc = [&](size_t bytes) -> char* {
        char* p = w + off;
        off = (off + bytes + 255) & ~(size_t)255;
        return p;
    };
    int* rowptr  = (int*)alloc((size_t)(N + 1) * sizeof(int));
    int* hist    = (int*)alloc((size_t)NH * sizeof(int));
    int* bktTot  = (int*)alloc((size_t)NBUK * sizeof(int));
    int* bktBase = (int*)alloc((size_t)(NBUK + 1) * sizeof(int));
    int* col     = (int*)alloc((size_t)M * sizeof(int));
    uint32_t* binned = (uint32_t*)alloc((size_t)E * sizeof(uint32_t));
    _Float16* xl1h = (_Float16*)alloc((size_t)N * H_DIM * 2);
    _Float16* xr1h = (_Float16*)alloc((size_t)N * H_DIM * 2);
    _Float16* h1h  = (_Float16*)alloc((size_t)N * H_DIM * 2);
    _Float16* xl2h = (_Float16*)alloc((size_t)N * K_DIM * 2);
    _Float16* xr2h = (_Float16*)alloc((size_t)N * K_DIM * 2);
    _Float16* Wg1  = (_Float16*)alloc((size_t)16384 * 2);
    _Float16* Wg2  = (_Float16*)alloc((size_t)2048 * 2);

    // W pre-swizzle (once) + CSR build
    k_swzW<<<2, 256, 0, stream>>>(W1l, W1r, W2l, W2r, Wg1, Wg2);
    k_hist<<<NCH, 256, 0, stream>>>(dstv, hist, E, CH, NBUK);
    k_scanBkt<<<NBUK, 256, 0, stream>>>(hist, bktTot);
    k_scanTot<<<1, 256, 0, stream>>>(bktTot, bktBase, NBUK);
    k_scatter<<<NCH, 256, 0, stream>>>(srcv, dstv, hist, bktBase, binned, E, CH, NBUK);
    k_fine2<<<NBUK, 256, 0, stream>>>(binned, bktBase, rowptr, col, N);

    // layers
    int g1Blocks = (N + 31) / 32;
    k_gemm1m<<<g1Blocks, 256, 0, stream>>>(X, Wg1, xl1h, xr1h, N);
    int nodeBlocks16 = (N + 15) / 16;
    k_att1<<<nodeBlocks16, 256, 0, stream>>>((const f16x8*)xl1h, (const f16x8*)xr1h,
                                             a1, b1, rowptr, col, (f16x8*)h1h, N);
    int g2Blocks = (N + 127) / 128;
    k_gemm2m<<<g2Blocks, 256, 0, stream>>>(h1h, Wg2, xl2h, xr2h, N);
    k_att2<<<nodeBlocks16, 256, 0, stream>>>((const half4*)xl2h, (const half4*)xr2h,
                                             a2, b2, rowptr, col, (float*)d_out, N);
}

// Round 6
// 236.920 us; speedup vs baseline: 1.0310x; 1.0310x over previous
//
#include <hip/hip_runtime.h>
#include <stdint.h>

#define F_DIM 128
#define H_DIM 64
#define K_DIM 16
#define BUK_SH 8
#define NCH 256

typedef _Float16 half2v __attribute__((ext_vector_type(2)));
typedef _Float16 half4 __attribute__((ext_vector_type(4)));
typedef _Float16 f16x8 __attribute__((ext_vector_type(8)));
typedef float f32x4 __attribute__((ext_vector_type(4)));

// 16B global->LDS DMA: LDS dest = wave-uniform base + lane*16, global src per-lane
__device__ __forceinline__ void gload_lds16(const void* g, void* l) {
    __builtin_amdgcn_global_load_lds(
        (const __attribute__((address_space(1))) void*)g,
        (__attribute__((address_space(3))) void*)l, 16, 0, 0);
}

// ---- radix-partition CSR build (5 kernels) -----------------------------
__global__ __launch_bounds__(256) void k_hist(const int* __restrict__ dst,
                                              int* __restrict__ hist,
                                              int E, int CH, int NBUK) {
    __shared__ int h[512];
    int t = threadIdx.x, c = blockIdx.x;
    for (int i = t; i < NBUK; i += 256) h[i] = 0;
    __syncthreads();
    int s = c * CH, e = min(s + CH, E);
    for (int i = s + t; i < e; i += 256) atomicAdd(&h[dst[i] >> BUK_SH], 1);
    __syncthreads();
    for (int i = t; i < NBUK; i += 256) hist[i * NCH + c] = h[i];
}

__global__ __launch_bounds__(256) void k_scanBkt(int* __restrict__ hist,
                                                 int* __restrict__ bktTot) {
    __shared__ int sh[256];
    int b = blockIdx.x, t = threadIdx.x;
    int v = hist[b * NCH + t];
    sh[t] = v;
    __syncthreads();
    for (int off = 1; off < 256; off <<= 1) {
        int x = (t >= off) ? sh[t - off] : 0;
        __syncthreads();
        sh[t] += x;
        __syncthreads();
    }
    hist[b * NCH + t] = sh[t] - v;
    if (t == 255) bktTot[b] = sh[255];
}

__global__ __launch_bounds__(256) void k_scanTot(const int* __restrict__ bktTot,
                                                 int* __restrict__ bktBase, int NBUK) {
    __shared__ int sh[256];
    int t = threadIdx.x;
    int i0 = 2 * t, i1 = 2 * t + 1;
    int v0 = (i0 < NBUK) ? bktTot[i0] : 0;
    int v1 = (i1 < NBUK) ? bktTot[i1] : 0;
    int s = v0 + v1;
    sh[t] = s;
    __syncthreads();
    for (int off = 1; off < 256; off <<= 1) {
        int x = (t >= off) ? sh[t - off] : 0;
        __syncthreads();
        sh[t] += x;
        __syncthreads();
    }
    int excl = sh[t] - s;
    if (i0 < NBUK) bktBase[i0] = excl;
    if (i1 < NBUK) bktBase[i1] = excl + v0;
    if (t == 255) bktBase[NBUK] = sh[255];
}

__global__ __launch_bounds__(256) void k_scatter(const int* __restrict__ src,
                                                 const int* __restrict__ dst,
                                                 const int* __restrict__ hist,
                                                 const int* __restrict__ bktBase,
                                                 uint32_t* __restrict__ binned,
                                                 int E, int CH, int NBUK) {
    __shared__ int ctr[512];
    int t = threadIdx.x, c = blockIdx.x;
    for (int i = t; i < NBUK; i += 256) ctr[i] = bktBase[i] + hist[i * NCH + c];
    __syncthreads();
    int s = c * CH, e = min(s + CH, E);
    for (int i = s + t; i < e; i += 256) {
        int d = dst[i];
        int pos = atomicAdd(&ctr[d >> BUK_SH], 1);
        binned[pos] = (uint32_t)src[i] | ((uint32_t)(d & 255) << 20);
    }
}

__global__ __launch_bounds__(256) void k_fine2(const uint32_t* __restrict__ binned,
                                               const int* __restrict__ bktBase,
                                               int* __restrict__ rowptr,
                                               int* __restrict__ col, int N) {
    __shared__ int h[256], sc[256], slotL[256];
    int b = blockIdx.x, t = threadIdx.x;
    int n0 = b << BUK_SH;
    int s = bktBase[b], e = bktBase[b + 1];
    h[t] = 0;
    __syncthreads();
    for (int i = s + t; i < e; i += 256) atomicAdd(&h[binned[i] >> 20], 1);
    __syncthreads();
    int v = h[t];
    sc[t] = v;
    __syncthreads();
    for (int off = 1; off < 256; off <<= 1) {
        int x = (t >= off) ? sc[t - off] : 0;
        __syncthreads();
        sc[t] += x;
        __syncthreads();
    }
    int excl = sc[t] - v;
    int n = n0 + t;
    int rowbase = s + n0;
    if (n < N) {
        int rp = rowbase + excl + t;
        rowptr[n] = rp;
        col[rp] = n;
        slotL[t] = rp + 1;
        if (n == N - 1) rowptr[N] = rp + v + 1;
    }
    __syncthreads();
    for (int i = s + t; i < e; i += 256) {
        uint32_t p = binned[i];
        int pos = atomicAdd(&slotL[p >> 20], 1);
        col[pos] = (int)(p & 0xFFFFFu);
    }
}

// ---- W pre-swizzle: fp32 -> fp16 MFMA-fragment layout, done ONCE -------
__global__ __launch_bounds__(256) void k_swzW(const float* __restrict__ W1l,
                                              const float* __restrict__ W1r,
                                              const float* __restrict__ W2l,
                                              const float* __restrict__ W2r,
                                              _Float16* __restrict__ Wg1,
                                              _Float16* __restrict__ Wg2) {
    int t = threadIdx.x;
    if (blockIdx.x == 0) {
        for (int i = t; i < 4096; i += 256) {
            int k = i >> 5, c4 = (i & 31) << 2;
            float4 v = (c4 < 64) ? *(const float4*)&W1l[k * 64 + c4]
                                 : *(const float4*)&W1r[k * 64 + (c4 - 64)];
            int s = k >> 5, q = (k >> 3) & 3, j = k & 7;
            float vv[4] = {v.x, v.y, v.z, v.w};
#pragma unroll
            for (int u = 0; u < 4; ++u) {
                int C = c4 + u, c = C >> 4, n = C & 15;
                Wg1[(((c * 4 + s) * 4 + q) * 16 + n) * 8 + j] = (_Float16)vv[u];
            }
        }
    } else {
        for (int i = t; i < 512; i += 256) {
            int k = i >> 3, c4 = (i & 7) << 2;
            float4 v = (c4 < 16) ? *(const float4*)&W2l[k * 16 + c4]
                                 : *(const float4*)&W2r[k * 16 + (c4 - 16)];
            int s = k >> 5, q = (k >> 3) & 3, j = k & 7;
            float vv[4] = {v.x, v.y, v.z, v.w};
#pragma unroll
            for (int u = 0; u < 4; ++u) {
                int C = c4 + u, c = C >> 4, n = C & 15;
                Wg2[(((c * 2 + s) * 4 + q) * 16 + n) * 8 + j] = (_Float16)vv[u];
            }
        }
    }
}

// ---- Layer 1 GEMM: 32 rows/block, c-split wave pairs, W via LDS-DMA ----
__global__ __launch_bounds__(256, 4) void k_gemm1m(
        const float* __restrict__ X, const _Float16* __restrict__ Wg,
        _Float16* __restrict__ xlh, _Float16* __restrict__ xrh, int N) {
    __shared__ _Float16 Ws[16384];        // 32 KB: W frags, reused for epilogue
    int t = threadIdx.x;
    int n0 = blockIdx.x * 32;
    int w = t >> 6, lane = t & 63, m = lane & 15, q = lane >> 4;
    int rowHalf = w >> 1, cHalf = w & 1;
    // DMA-stage the 32 KB W table: 2048 x 16B chunks, 8 per thread
    {
        int base = w * 64;                // chunk index of this wave's lane 0
#pragma unroll
        for (int i = 0; i < 8; ++i) {
            int ch = i * 256 + base;
            gload_lds16(&Wg[(long)(ch + lane) * 8], &Ws[(long)ch * 8]);
        }
    }
    // prefetch this wave's 16 X rows (fp32), all 8 loads co-outstanding
    int r0 = n0 + rowHalf * 16 + m;
    int rc = (r0 < N) ? r0 : (N - 1);
    const float* p0 = X + (long)rc * 128 + q * 8;
    float4 xf[8];
#pragma unroll
    for (int s = 0; s < 4; ++s) {
        xf[2 * s]     = *(const float4*)(p0 + s * 32);
        xf[2 * s + 1] = *(const float4*)(p0 + s * 32 + 4);
    }
    f16x8 af[4];
#pragma unroll
    for (int s = 0; s < 4; ++s) {
        af[s][0] = (_Float16)xf[2 * s].x;     af[s][1] = (_Float16)xf[2 * s].y;
        af[s][2] = (_Float16)xf[2 * s].z;     af[s][3] = (_Float16)xf[2 * s].w;
        af[s][4] = (_Float16)xf[2 * s + 1].x; af[s][5] = (_Float16)xf[2 * s + 1].y;
        af[s][6] = (_Float16)xf[2 * s + 1].z; af[s][7] = (_Float16)xf[2 * s + 1].w;
    }
    __syncthreads();                      // drains the W DMA (vmcnt) + all waves
    f32x4 acc[4];
#pragma unroll
    for (int c = 0; c < 4; ++c) acc[c] = (f32x4){0.f, 0.f, 0.f, 0.f};
#pragma unroll
    for (int s = 0; s < 4; ++s)
#pragma unroll
        for (int c = 0; c < 4; ++c) {
            int cc = cHalf * 4 + c;
            f16x8 b = *(const f16x8*)&Ws[(((cc * 4 + s) * 4 + q) * 16 + m) * 8];
            acc[c] = __builtin_amdgcn_mfma_f32_16x16x32_f16(af[s], b, acc[c], 0, 0, 0);
        }
    __syncthreads();                      // all waves done reading Ws
    // per-wave transpose region (16 rows x 64 cols, stride 76 halves)
    _Float16* Tw = &Ws[w * 2048];
#pragma unroll
    for (int c = 0; c < 4; ++c)
#pragma unroll
        for (int r = 0; r < 4; ++r)
            Tw[(q * 4 + r) * 76 + c * 16 + m] = (_Float16)acc[c][r];
    // coalesced stores: wave writes 8 rows x 128B contiguous per pass
#pragma unroll
    for (int p = 0; p < 2; ++p) {
        int lr = p * 8 + (lane >> 3);
        int chk = lane & 7;
        f16x8 v = *(const f16x8*)&Tw[lr * 76 + chk * 8];
        int gn = n0 + rowHalf * 16 + lr;
        if (gn < N) {
            if (cHalf == 0) *(f16x8*)&xlh[(long)gn * 64 + chk * 8] = v;
            else            *(f16x8*)&xrh[(long)gn * 64 + chk * 8] = v;
        }
    }
}

// ---- Layer 2 GEMM: 32 rows/wave, W2 staged in LDS, H prefetched --------
__global__ __launch_bounds__(256, 4) void k_gemm2m(
        const _Float16* __restrict__ Hm, const _Float16* __restrict__ Wg2,
        _Float16* __restrict__ xlh, _Float16* __restrict__ xrh, int N) {
    __shared__ _Float16 Ws2[1024];        // 2 KB W frags
    __shared__ _Float16 T[4][32 * 40];    // per-wave transpose, stride 40
    int t = threadIdx.x;
    int n0 = blockIdx.x * 128;
    int w = t >> 6, lane = t & 63, m = lane & 15, q = lane >> 4;
    if (t < 128) *(f16x8*)&Ws2[t * 8] = *(const f16x8*)&Wg2[t * 8];
    // prefetch H fragments: 2 subs x 2 s-steps (all in flight)
    const f16x8 zh = {0, 0, 0, 0, 0, 0, 0, 0};
    f16x8 a[2][2];
#pragma unroll
    for (int sub = 0; sub < 2; ++sub) {
        int row = n0 + w * 32 + sub * 16 + m;
        bool vr = row < N;
#pragma unroll
        for (int s = 0; s < 2; ++s)
            a[sub][s] = vr ? *(const f16x8*)&Hm[(long)row * 64 + s * 32 + q * 8] : zh;
    }
    __syncthreads();
    f32x4 acc[2][2];
#pragma unroll
    for (int sub = 0; sub < 2; ++sub)
#pragma unroll
        for (int c = 0; c < 2; ++c) acc[sub][c] = (f32x4){0.f, 0.f, 0.f, 0.f};
#pragma unroll
    for (int s = 0; s < 2; ++s)
#pragma unroll
        for (int c = 0; c < 2; ++c) {
            f16x8 b = *(const f16x8*)&Ws2[(((c * 2 + s) * 4 + q) * 16 + m) * 8];
#pragma unroll
            for (int sub = 0; sub < 2; ++sub)
                acc[sub][c] = __builtin_amdgcn_mfma_f32_16x16x32_f16(a[sub][s], b, acc[sub][c], 0, 0, 0);
        }
    _Float16* Tw = T[w];
#pragma unroll
    for (int sub = 0; sub < 2; ++sub)
#pragma unroll
    for (int c = 0; c < 2; ++c)
#pragma unroll
    for (int r = 0; r < 4; ++r)
        Tw[(sub * 16 + q * 4 + r) * 40 + c * 16 + m] = (_Float16)acc[sub][c][r];
    int lr = lane >> 1;
    int gn = n0 + w * 32 + lr;
#pragma unroll
    for (int p = 0; p < 2; ++p) {
        int cc = p * 2 + (lane & 1);
        f16x8 v = *(const f16x8*)&Tw[lr * 40 + cc * 8];
        if (gn < N) {
            if (cc < 2) *(f16x8*)&xlh[(long)gn * 16 + cc * 8] = v;
            else        *(f16x8*)&xrh[(long)gn * 16 + (cc - 2) * 8] = v;
        }
    }
}

// ---- Attention layer 1: 16 lanes/node, 2-stage software pipeline -------
// lane layout: [node_sub 2b][g 1b][q 3b]; q = dim octet, g = edge group.
// While edge k computes, the gather for edge k+2 is in flight and the col
// index for edge k+4 is being loaded -- breaks the col->gather->compute
// loop-carried latency chain.
__global__ void k_att1(const f16x8* __restrict__ xlh, const f16x8* __restrict__ xrh,
                       const float* __restrict__ a1, const float* __restrict__ b1,
                       const int* __restrict__ rowptr, const int* __restrict__ col,
                       f16x8* __restrict__ hout, int N) {
    int n = (int)((blockIdx.x * (unsigned)blockDim.x + threadIdx.x) >> 4);
    int lane = threadIdx.x & 63;
    if (n >= N) return;
    int q = lane & 7;          // dim octet: dims q*8 .. q*8+7
    int g = (lane >> 3) & 1;   // edge group 0..1
    float4 af0 = ((const float4*)a1)[q * 2 + 0];
    float4 af1 = ((const float4*)a1)[q * 2 + 1];
    half2v a01 = {(_Float16)af0.x, (_Float16)af0.y};
    half2v a23 = {(_Float16)af0.z, (_Float16)af0.w};
    half2v a45 = {(_Float16)af1.x, (_Float16)af1.y};
    half2v a67 = {(_Float16)af1.z, (_Float16)af1.w};
    f16x8 xrv = xrh[(long)n * 8 + q];
    int jb = rowptr[n], je = rowptr[n + 1];
    int j0 = jb + g, jlast = je - 1;           // self-loop => jlast >= jb
    int d = je - jb - g;
    int T = (d > 0) ? ((d + 1) >> 1) : 0;      // edges for this group
    float l = 0.f;
    float o[8] = {0.f, 0.f, 0.f, 0.f, 0.f, 0.f, 0.f, 0.f};
    auto jidx = [&](int k) { int j = j0 + 2 * k; return (j < jlast) ? j : jlast; };
    auto edge = [&](const f16x8& xh) {
        f16x8 t = xh + xrv;
        f16x8 u = __builtin_elementwise_max(t, t * (_Float16)0.2f);
        half2v ua = {u[0], u[1]}, ub = {u[2], u[3]}, uc = {u[4], u[5]}, ud = {u[6], u[7]};
        float e = __builtin_amdgcn_fdot2(ua, a01,
                   __builtin_amdgcn_fdot2(ub, a23,
                    __builtin_amdgcn_fdot2(uc, a45,
                     __builtin_amdgcn_fdot2(ud, a67, 0.f, false), false), false), false);
#pragma unroll
        for (int off = 1; off < 8; off <<= 1) e += __shfl_xor(e, off, 8);
        float c = __expf(e);
        l += c;
#pragma unroll
        for (int i = 0; i < 8; ++i) o[i] = fmaf(c, (float)xh[i], o[i]);
    };
    // prologue: edges 0,1 gathered; col for edges 2,3 prefetched
    f16x8 xA = xlh[(long)col[jidx(0)] * 8 + q];
    f16x8 xB = xlh[(long)col[jidx(1)] * 8 + q];
    int cA = col[jidx(2)];
    int cB = col[jidx(3)];
    int k = 0;
    for (; k + 2 <= T; k += 2) {
        int cA2 = col[jidx(k + 4)];            // cols for edges k+4,k+5
        int cB2 = col[jidx(k + 5)];
        edge(xA);
        xA = xlh[(long)cA * 8 + q];            // gather for edge k+2
        edge(xB);
        xB = xlh[(long)cB * 8 + q];            // gather for edge k+3
        cA = cA2; cB = cB2;
    }
    if (k < T) edge(xA);                        // odd remainder
    // merge the 2 edge groups (lane bit 3)
    l += __shfl_xor(l, 8);
#pragma unroll
    for (int i = 0; i < 8; ++i) o[i] += __shfl_xor(o[i], 8);
    if (g == 0) {
        float4 bv0 = ((const float4*)b1)[q * 2 + 0];
        float4 bv1 = ((const float4*)b1)[q * 2 + 1];
        float bb[8] = {bv0.x, bv0.y, bv0.z, bv0.w, bv1.x, bv1.y, bv1.z, bv1.w};
        float rl = 1.f / l;
        f16x8 hv;
#pragma unroll
        for (int i = 0; i < 8; ++i) {
            float h = o[i] * rl + bb[i];
            h = (h > 0.f) ? h : (__expf(h) - 1.f);
            hv[i] = (_Float16)h;
        }
        hout[(long)n * 8 + q] = hv;
    }
}

// ---- Attention layer 2 + softmax: 16 lanes/node, pipelined -------------
// lane layout: [node_sub 2b][g 2b][q 2b]; q = dim quad, g = edge group 0..3.
__global__ void k_att2(const half4* __restrict__ xlh, const half4* __restrict__ xrh,
                       const float* __restrict__ a2, const float* __restrict__ b2v,
                       const int* __restrict__ rowptr, const int* __restrict__ col,
                       float* __restrict__ out, int N) {
    int n = (int)((blockIdx.x * (unsigned)blockDim.x + threadIdx.x) >> 4);
    int lane = threadIdx.x & 63;
    if (n >= N) return;
    int q = lane & 3;
    int g = (lane >> 2) & 3;
    float4 af = ((const float4*)a2)[q];
    half2v alo = {(_Float16)af.x, (_Float16)af.y};
    half2v ahi = {(_Float16)af.z, (_Float16)af.w};
    half4 xrv = xrh[(long)n * 4 + q];
    int jb = rowptr[n], je = rowptr[n + 1];
    int j0 = jb + g, jlast = je - 1;
    int d = je - jb - g;
    int T = (d > 0) ? ((d + 3) >> 2) : 0;
    float l = 0.f;
    float4 o = {0.f, 0.f, 0.f, 0.f};
    auto jidx = [&](int k) { int j = j0 + 4 * k; return (j < jlast) ? j : jlast; };
    auto edge = [&](const half4& xh) {
        half4 t = xh + xrv;
        half4 u = __builtin_elementwise_max(t, t * (_Float16)0.2f);
        half2v ulo = {u.x, u.y}, uhi = {u.z, u.w};
        float e = __builtin_amdgcn_fdot2(ulo, alo,
                   __builtin_amdgcn_fdot2(uhi, ahi, 0.f, false), false);
        e += __shfl_xor(e, 1, 4);
        e += __shfl_xor(e, 2, 4);
        float c = __expf(e);
        l += c;
        o.x = fmaf(c, (float)xh.x, o.x);
        o.y = fmaf(c, (float)xh.y, o.y);
        o.z = fmaf(c, (float)xh.z, o.z);
        o.w = fmaf(c, (float)xh.w, o.w);
    };
    half4 xA = xlh[(long)col[jidx(0)] * 4 + q];
    half4 xB = xlh[(long)col[jidx(1)] * 4 + q];
    int cA = col[jidx(2)];
    int cB = col[jidx(3)];
    int k = 0;
    for (; k + 2 <= T; k += 2) {
        int cA2 = col[jidx(k + 4)];
        int cB2 = col[jidx(k + 5)];
        edge(xA);
        xA = xlh[(long)cA * 4 + q];
        edge(xB);
        xB = xlh[(long)cB * 4 + q];
        cA = cA2; cB = cB2;
    }
    if (k < T) edge(xA);
    // merge the 4 edge groups (lane bits 2,3)
#pragma unroll
    for (int off = 4; off <= 8; off <<= 1) {
        l   += __shfl_xor(l, off);
        o.x += __shfl_xor(o.x, off);
        o.y += __shfl_xor(o.y, off);
        o.z += __shfl_xor(o.z, off);
        o.w += __shfl_xor(o.w, off);
    }
    if (g == 0) {
        float4 bv = ((const float4*)b2v)[q];
        float rl = 1.f / l;
        float4 z;
        z.x = o.x * rl + bv.x;
        z.y = o.y * rl + bv.y;
        z.z = o.z * rl + bv.z;
        z.w = o.w * rl + bv.w;
        float mx = fmaxf(fmaxf(z.x, z.y), fmaxf(z.z, z.w));
        mx = fmaxf(mx, __shfl_xor(mx, 1, 4));
        mx = fmaxf(mx, __shfl_xor(mx, 2, 4));
        float4 ez;
        ez.x = __expf(z.x - mx); ez.y = __expf(z.y - mx);
        ez.z = __expf(z.z - mx); ez.w = __expf(z.w - mx);
        float ss = ez.x + ez.y + ez.z + ez.w;
        ss += __shfl_xor(ss, 1, 4);
        ss += __shfl_xor(ss, 2, 4);
        float rs = 1.f / ss;
        ez.x *= rs; ez.y *= rs; ez.z *= rs; ez.w *= rs;
        ((float4*)out)[(long)n * 4 + q] = ez;
    }
}

// ---- launch ------------------------------------------------------------
extern "C" void kernel_launch(void* const* d_in, const int* in_sizes, int n_in,
                              void* d_out, int out_size, void* d_ws, size_t ws_size,
                              hipStream_t stream) {
    const float* X   = (const float*)d_in[0];
    const int*   ei  = (const int*)d_in[1];
    const float* W1l = (const float*)d_in[3];
    const float* W1r = (const float*)d_in[4];
    const float* a1  = (const float*)d_in[5];
    const float* b1  = (const float*)d_in[6];
    const float* W2l = (const float*)d_in[7];
    const float* W2r = (const float*)d_in[8];
    const float* a2  = (const float*)d_in[9];
    const float* b2  = (const float*)d_in[10];

    int N = in_sizes[0] / F_DIM;
    int E = in_sizes[1] / 2;
    int M = E + N;
    int NBUK = (N + 255) >> BUK_SH;
    int NH = NBUK * NCH;
    int CH = (E + NCH - 1) / NCH;
    const int* srcv = ei;
    const int* dstv = ei + E;

    char* w = (char*)d_ws;
    size_t off = 0;
    auto alloc = [&](size_t bytes) -> char* {
        char* p = w + off;
        off = (off + bytes + 255) & ~(size_t)255;
        return p;
    };
    int* rowptr  = (int*)alloc((size_t)(N + 1) * sizeof(int));
    int* hist    = (int*)alloc((size_t)NH * sizeof(int));
    int* bktTot  = (int*)alloc((size_t)NBUK * sizeof(int));
    int* bktBase = (int*)alloc((size_t)(NBUK + 1) * sizeof(int));
    int* col     = (int*)alloc((size_t)M * sizeof(int));
    uint32_t* binned = (uint32_t*)alloc((size_t)E * sizeof(uint32_t));
    _Float16* xl1h = (_Float16*)alloc((size_t)N * H_DIM * 2);
    _Float16* xr1h = (_Float16*)alloc((size_t)N * H_DIM * 2);
    _Float16* h1h  = (_Float16*)alloc((size_t)N * H_DIM * 2);
    _Float16* xl2h = (_Float16*)alloc((size_t)N * K_DIM * 2);
    _Float16* xr2h = (_Float16*)alloc((size_t)N * K_DIM * 2);
    _Float16* Wg1  = (_Float16*)alloc((size_t)16384 * 2);
    _Float16* Wg2  = (_Float16*)alloc((size_t)2048 * 2);

    // W pre-swizzle (once) + CSR build
    k_swzW<<<2, 256, 0, stream>>>(W1l, W1r, W2l, W2r, Wg1, Wg2);
    k_hist<<<NCH, 256, 0, stream>>>(dstv, hist, E, CH, NBUK);
    k_scanBkt<<<NBUK, 256, 0, stream>>>(hist, bktTot);
    k_scanTot<<<1, 256, 0, stream>>>(bktTot, bktBase, NBUK);
    k_scatter<<<NCH, 256, 0, stream>>>(srcv, dstv, hist, bktBase, binned, E, CH, NBUK);
    k_fine2<<<NBUK, 256, 0, stream>>>(binned, bktBase, rowptr, col, N);

    // layers
    int g1Blocks = (N + 31) / 32;
    k_gemm1m<<<g1Blocks, 256, 0, stream>>>(X, Wg1, xl1h, xr1h, N);
    int nodeBlocks16 = (N + 15) / 16;
    k_att1<<<nodeBlocks16, 256, 0, stream>>>((const f16x8*)xl1h, (const f16x8*)xr1h,
                                             a1, b1, rowptr, col, (f16x8*)h1h, N);
    int g2Blocks = (N + 127) / 128;
    k_gemm2m<<<g2Blocks, 256, 0, stream>>>(h1h, Wg2, xl2h, xr2h, N);
    k_att2<<<nodeBlocks16, 256, 0, stream>>>((const half4*)xl2h, (const half4*)xr2h,
                                             a2, b2, rowptr, col, (float*)d_out, N);
}